// Round 1
// baseline (417.355 us; speedup 1.0000x reference)
//
#include <hip/hip_runtime.h>

// out[n, d] = x[n, d] * w[d]   with N = DIM = 8192, fp32.
// Memory-bound: 512 MiB total HBM traffic -> ~85 us floor at 6.3 TB/s.
// One float4 per thread; weight quad index = i & (DIM/4 - 1).

#define DIM 8192

__global__ __launch_bounds__(256) void scale_cols_f4(
    const float4* __restrict__ x4,
    const float4* __restrict__ w4,
    float4* __restrict__ out4,
    unsigned int n4)
{
    unsigned int i = blockIdx.x * 256u + threadIdx.x;
    if (i >= n4) return;
    const unsigned int c = i & (DIM / 4 - 1);   // column quad within row
    float4 xv = x4[i];
    float4 wv = w4[c];
    float4 o;
    o.x = xv.x * wv.x;
    o.y = xv.y * wv.y;
    o.z = xv.z * wv.z;
    o.w = xv.w * wv.w;
    out4[i] = o;
}

extern "C" void kernel_launch(void* const* d_in, const int* in_sizes, int n_in,
                              void* d_out, int out_size, void* d_ws, size_t ws_size,
                              hipStream_t stream)
{
    const float4* x4  = (const float4*)d_in[0];   // (N, DIM) fp32
    const float4* w4  = (const float4*)d_in[1];   // (DIM,)   fp32
    float4* out4      = (float4*)d_out;           // (N, DIM) fp32

    const unsigned int n4 = (unsigned int)((long long)out_size / 4); // 16,777,216
    const unsigned int blocks = (n4 + 255u) / 256u;                  // 65,536
    scale_cols_f4<<<blocks, 256, 0, stream>>>(x4, w4, out4, n4);
}

// Round 3
// 412.096 us; speedup vs baseline: 1.0128x; 1.0128x over previous
//
#include <hip/hip_runtime.h>

// out[n, d] = x[n, d] * w[d]   N = DIM = 8192, fp32.
// Memory-bound streaming: 536 MB HBM traffic -> ~92 us floor at ~5.8 TB/s r+w.
//
// Each thread owns ONE column-quad c (w loaded once, kept in VGPRs) and
// streams ROWS_PER_BLOCK rows with all loads issued back-to-back (MLP=8).
// Nontemporal hints on x/out: zero-reuse streaming data.
// Note: nontemporal builtins need a true vector type, not HIP_vector_type.

typedef float vf4 __attribute__((ext_vector_type(4)));

#define DIM 8192
#define QPR (DIM / 4)          // 2048 quads per row
#define TPB 256                // threads per block
#define CB_PER_ROW (QPR / TPB) // 8 column-blocks tile one row's width
#define ROWS_PER_BLOCK 8

__global__ __launch_bounds__(TPB) void scale_cols_f4_v2(
    const vf4* __restrict__ x4,
    const vf4* __restrict__ w4,
    vf4* __restrict__ out4)
{
    const unsigned int cb = blockIdx.x & (CB_PER_ROW - 1);      // column tile
    const unsigned int rb = blockIdx.x >> 3;                    // row group
    const unsigned int c  = cb * TPB + threadIdx.x;             // column quad
    const unsigned int r0 = rb * ROWS_PER_BLOCK;

    const vf4 wv = w4[c];   // one cached load per thread, amortized 8x

    const unsigned int idx = r0 * QPR + c;
    vf4 xv[ROWS_PER_BLOCK];
    #pragma unroll
    for (int k = 0; k < ROWS_PER_BLOCK; ++k) {
        xv[k] = __builtin_nontemporal_load(&x4[idx + (unsigned)k * QPR]);
    }
    #pragma unroll
    for (int k = 0; k < ROWS_PER_BLOCK; ++k) {
        __builtin_nontemporal_store(xv[k] * wv, &out4[idx + (unsigned)k * QPR]);
    }
}

extern "C" void kernel_launch(void* const* d_in, const int* in_sizes, int n_in,
                              void* d_out, int out_size, void* d_ws, size_t ws_size,
                              hipStream_t stream)
{
    const vf4* x4  = (const vf4*)d_in[0];   // (N, DIM) fp32
    const vf4* w4  = (const vf4*)d_in[1];   // (DIM,)   fp32
    vf4* out4      = (vf4*)d_out;           // (N, DIM) fp32

    // 8192 rows / 8 rows-per-block * 8 column-blocks = 8192 blocks
    const unsigned int blocks = (8192 / ROWS_PER_BLOCK) * CB_PER_ROW;
    scale_cols_f4_v2<<<blocks, TPB, 0, stream>>>(x4, w4, out4);
}